// Round 1
// baseline (229.095 us; speedup 1.0000x reference)
//
#include <hip/hip_runtime.h>

typedef unsigned short u16;
typedef unsigned int u32;
typedef float f32x4 __attribute__((ext_vector_type(4)));
typedef short bf16x8 __attribute__((ext_vector_type(8)));

#define NB 8
#define FH 37
#define FW 50
#define FHW 1850
#define MTOT 14800
#define CIN 512
#define KTOT 4608
#define HP 39
#define WP 52
#define ANCH 16650
#define NG 20

// k_pre block ranges
#define ZB 356            // pad-ring zero
#define WTB 512           // w3 repack (LDS transpose, 1 block per n)
#define WHB 128           // head-weight repack
#define TRB 3712          // NHWC transpose: 58 hw x 8 ctile x 8 img, u32 stores
#define PRE_TOT (ZB + WTB + WHB + TRB)

// k_conv block ranges
#define CONVB 960         // 116 mb x 8 nb (XCD swizzle; 32 dead blocks)
#define IOB 528           // 66 x 8 iou blocks ride along

// ---------- helpers ----------
__device__ __forceinline__ u16 f2bf(float f) {
    u32 u = __float_as_uint(f);
    u += 0x7fffu + ((u >> 16) & 1u);   // round-to-nearest-even
    return (u16)(u >> 16);
}

__device__ __forceinline__ void gl2lds16(const u16* g, u16* l) {
    __builtin_amdgcn_global_load_lds((const __attribute__((address_space(1))) void*)(g),
                                     (__attribute__((address_space(3))) void*)(l),
                                     16, 0, 0);
}

__device__ __forceinline__ void anchor_box(int a, float& x1, float& y1, float& x2, float& y2) {
    int x = a / 333;
    int rem = a - x * 333;
    int y = rem / 9;
    int r2 = rem - y * 9;
    int si = r2 / 3;
    int bi = r2 - si * 3;
    float s = (float)(8 << si);
    float fx = (float)x, fy = (float)y;
    float ax1, ay1, ax2, ay2;
    if (bi == 0)      { float h = s * 0.5f;  ax1 = fx - h; ay1 = fy - h; ax2 = fx + h; ay2 = fy + h; }
    else if (bi == 1) { float q = s * 0.25f; ax1 = fx - s; ay1 = fy - q; ax2 = fx + s; ay2 = fy + q; }
    else              { float q = s * 0.25f; ax1 = fx - q; ay1 = fy - s; ax2 = fx + q; ay2 = fy + s; }
    x1 = ax1 * 16.f; y1 = ay1 * 16.f; x2 = ax2 * 16.f; y2 = ay2 * 16.f;
}

// ---------- fused prep ----------
__global__ __launch_bounds__(256) void k_pre(u16* __restrict__ apad,
                                             const float* __restrict__ w3, u16* __restrict__ wt,
                                             const float* __restrict__ wc, const float* __restrict__ wb,
                                             u16* __restrict__ whd,
                                             const float* __restrict__ feats) {
    __shared__ __attribute__((aligned(16))) char smraw[18432];
    int blk = blockIdx.x;
    int t = threadIdx.x;

    if (blk < ZB) {
        // zero only the 1-px pad ring (interior overwritten by transpose)
        uint4* apad4 = (uint4*)apad;
        int i = blk * 256 + t;               // < 91136
        int img = i / 11392;
        int r = i - img * 11392;
        int u4;
        if (r < 3328) u4 = r;                                   // row 0
        else if (r < 6656) u4 = 126464 + (r - 3328);            // row 38
        else {
            int rp = r - 6656;
            int h = 1 + (rp >> 7);
            int c2 = rp & 127;
            int col = (c2 & 64) ? 51 : 0;
            u4 = (h * 52 + col) * 64 + (c2 & 63);
        }
        apad4[img * 129792 + u4] = make_uint4(0u, 0u, 0u, 0u);
    } else if (blk < ZB + WTB) {
        // w3[n] (512,3,3) -> wt[n][tap*512+ci], coalesced via LDS transpose
        float* lt = (float*)smraw;           // 4608 floats
        int n = blk - ZB;
        const float* src = w3 + n * KTOT;
        for (int i = t; i < KTOT; i += 256) lt[i] = src[i];
        __syncthreads();
        u16* dst = wt + n * KTOT;
        for (int o = t; o < KTOT; o += 256) {
            int tap = o >> 9, ci = o & 511;
            dst[o] = f2bf(lt[ci * 9 + tap]);
        }
    } else if (blk < ZB + WTB + WHB) {
        int i = (blk - ZB - WTB) * 256 + t;
        int n = i >> 9;
        int ci = i & 511;
        float v = 0.f;
        if (n < 18) v = wc[n * 512 + ci];
        else if (n < 54) v = wb[(n - 18) * 512 + ci];
        whd[i] = f2bf(v);
    } else {
        // feats (B,512,37,50) f32 -> apad (B,39,52,512) bf16 interior.
        // Tile: 32 hw x 64 c; stores pack 2 channels/lane (u32, 128-B segments).
        float* tile = (float*)smraw;         // 64 x 33 floats
        int q = blk - ZB - WTB - WHB;
        int xt = q % 58;
        int r2 = q / 58;
        int ct = r2 & 7;                     // 8 c-tiles of 64
        int img = r2 >> 3;
        int hw0 = xt * 32, c0 = ct * 64;
        int lx = t & 31, ly = t >> 5;        // ly 0..7
        #pragma unroll
        for (int rr = 0; rr < 8; rr++) {
            int cl = ly + rr * 8;            // 0..63
            int hw = hw0 + lx;
            if (hw < FHW) tile[cl * 33 + lx] = feats[(img * 512 + c0 + cl) * FHW + hw];
        }
        __syncthreads();
        #pragma unroll
        for (int rr = 0; rr < 4; rr++) {
            int hwl = ly + rr * 8;           // 0..31
            int hw2 = hw0 + hwl;
            if (hw2 < FHW) {
                int h = hw2 / FW, w = hw2 - h * FW;
                float v0 = tile[(2 * lx) * 33 + hwl];
                float v1 = tile[(2 * lx + 1) * 33 + hwl];
                u32 pk = (u32)f2bf(v0) | ((u32)f2bf(v1) << 16);
                u32* dst = (u32*)&apad[(((img * HP) + h + 1) * WP + (w + 1)) * 512 + c0];
                dst[lx] = pk;
            }
        }
    }
}

// ---------- 3x3 conv as implicit GEMM + IoU tail ----------
// BM=128 BN=64 BK=64 full-K, bf16 act epilogue. XCD decode: all 8 nb of one
// mb share L%8 (one XCD) for A-tile L2 reuse. No fences/atomics (R6/R7 lessons).
// R1: software-pipelined K-loop (T3 minimum 2-phase): static LDS double-buffer
// (A0/B0, A1/B1), STAGE(next) issued BEFORE compute(cur), single barrier per
// K-step. Loads for tile t+1 stay in flight under tile t's ds_read+MFMA; the
// compiler's pre-barrier vmcnt(0) is then exactly the required semantics.
__global__ __launch_bounds__(256) void k_conv(const u16* __restrict__ apad,
                                              const u16* __restrict__ wt,
                                              const float* __restrict__ b3,
                                              u16* __restrict__ act,
                                              const float* __restrict__ gt,
                                              const float* __restrict__ im,
                                              float* __restrict__ iou_out,
                                              float* __restrict__ lab) {
    __shared__ __attribute__((aligned(16))) char sm[49152];
    __shared__ int idxs;
    int L = blockIdx.x;
    int tid = threadIdx.x;

    if (L < CONVB) {
        // double-buffered tiles: A (128x64 bf16, 16 KB) + B (64x64 bf16, 8 KB) x2
        u16* A0 = (u16*)sm;                 // bytes [0, 16384)
        u16* B0 = A0 + 8192;                // bytes [16384, 24576)
        u16* A1 = (u16*)(sm + 24576);       // bytes [24576, 40960)
        u16* B1 = A1 + 8192;                // bytes [40960, 49152)
        int mb = (L & 7) + 8 * (L >> 6);
        int nb = (L >> 3) & 7;
        if (mb >= 116) return;
        int wave = tid >> 6, lane = tid & 63;
        int m0 = mb * 128;
        int n0 = nb * 64;
        int wr = wave >> 1, wn = wave & 1;
        int lm = lane & 15, lq = lane >> 4;
        int l7 = lm & 7;

        f32x4 acc[4][2] = {};

        int rloc = tid >> 3;
        int cg = (tid & 7) ^ (rloc & 7);
        int aBase[4], bBase[2];
        for (int i = 0; i < 4; i++) {
            int m = m0 + i * 32 + rloc; if (m > MTOT - 1) m = MTOT - 1;
            int b = m / FHW; int hw = m - b * FHW;
            int h = hw / FW; int w = hw - h * FW;
            aBase[i] = ((b * HP + h) * WP + w) * 512 + cg * 8;
        }
        for (int j = 0; j < 2; j++)
            bBase[j] = (n0 + j * 32 + rloc) * KTOT + cg * 8;

        // per-wave LDS destinations (wave-uniform base; HW adds lane*16B)
        int aOff0 = wave * 512;
        int aOff1 = 2048 + wave * 512;
        int aOff2 = 4096 + wave * 512;
        int aOff3 = 6144 + wave * 512;
        int bOff0 = wave * 512;
        int bOff1 = 2048 + wave * 512;

#define STAGE(Abuf, Bbuf, KK) do {                                         \
            int tap_ = (KK) >> 9;                                          \
            int ci0_ = (KK) & 511;                                         \
            int dy_ = tap_ / 3, dx_ = tap_ - dy_ * 3;                      \
            int aOfs_ = (dy_ * WP + dx_) * 512 + ci0_;                     \
            gl2lds16(apad + aBase[0] + aOfs_, (Abuf) + aOff0);             \
            gl2lds16(apad + aBase[1] + aOfs_, (Abuf) + aOff1);             \
            gl2lds16(apad + aBase[2] + aOfs_, (Abuf) + aOff2);             \
            gl2lds16(apad + aBase[3] + aOfs_, (Abuf) + aOff3);             \
            gl2lds16(wt + bBase[0] + (KK), (Bbuf) + bOff0);                \
            gl2lds16(wt + bBase[1] + (KK), (Bbuf) + bOff1);                \
        } while (0)

#define COMPUTE(Abuf, Bbuf) do {                                           \
            bf16x8 a_[2][4], b_[2][2];                                     \
            _Pragma("unroll")                                              \
            for (int ks = 0; ks < 2; ks++) {                               \
                int slotb = ((ks * 4 + lq) ^ l7) * 8;                      \
                _Pragma("unroll")                                          \
                for (int i = 0; i < 4; i++)                                \
                    a_[ks][i] = *(const bf16x8*)&(Abuf)[(wr * 64 + i * 16 + lm) * 64 + slotb]; \
                _Pragma("unroll")                                          \
                for (int j = 0; j < 2; j++)                                \
                    b_[ks][j] = *(const bf16x8*)&(Bbuf)[(wn * 32 + j * 16 + lm) * 64 + slotb]; \
            }                                                              \
            _Pragma("unroll")                                              \
            for (int ks = 0; ks < 2; ks++)                                 \
                _Pragma("unroll")                                          \
                for (int i = 0; i < 4; i++)                                \
                    _Pragma("unroll")                                      \
                    for (int j = 0; j < 2; j++)                            \
                        acc[i][j] = __builtin_amdgcn_mfma_f32_16x16x32_bf16(a_[ks][i], b_[ks][j], acc[i][j], 0, 0, 0); \
        } while (0)

        // prologue: tile 0 into buf0
        STAGE(A0, B0, 0);
        __syncthreads();

        // 72 K-tiles, unrolled x2 so buffer selection is static
        for (int kk = 0; kk < KTOT; kk += 128) {
            STAGE(A1, B1, kk + 64);          // kk+64 <= 4544 < KTOT always
            COMPUTE(A0, B0);
            __syncthreads();                 // drains vmcnt: tile kk+64 landed
            if (kk + 128 < KTOT) STAGE(A0, B0, kk + 128);
            COMPUTE(A1, B1);
            __syncthreads();                 // drains vmcnt: tile kk+128 landed
        }
#undef STAGE
#undef COMPUTE

        // epilogue: bias + relu + bf16 act
        for (int j = 0; j < 2; j++) {
            int n = n0 + wn * 32 + j * 16 + lm;
            float bias = b3[n];
            for (int i = 0; i < 4; i++) {
                int mb2 = m0 + wr * 64 + i * 16 + lq * 4;
                for (int r = 0; r < 4; r++) {
                    int m = mb2 + r;
                    if (m < MTOT) {
                        float v = acc[i][j][r] + bias;
                        act[m * 512 + n] = f2bf(v > 0.f ? v : 0.f);
                    }
                }
            }
        }
    } else {
        // IoU matrix + labels (idx fused)
        float* g4 = (float*)sm;              // 80 floats
        float* imv = g4 + 80;                // 2
        float* buf = g4 + 84;                // 256*20
        int q = L - CONVB;
        int at = q % 66;
        int b = q / 66;
        int t = tid;
        if (t < NG * 4) g4[t] = gt[b * NG * 4 + t];
        if (t < 2) imv[t] = im[t];
        __syncthreads();
        if (t == 0) {
            float x1, y1, x2, y2;
            anchor_box(19, x1, y1, x2, y2);
            bool inside = (x1 >= 0.f) && (y1 >= 0.f) && (x2 < imv[1]) && (y2 < imv[0]);
            float aa = (x2 - x1) * (y2 - y1);
            float best = -1.f; int bg = 0;
            for (int g2 = 0; g2 < NG; g2++) {
                float gx1 = g4[g2 * 4], gy1 = g4[g2 * 4 + 1], gx2 = g4[g2 * 4 + 2], gy2 = g4[g2 * 4 + 3];
                float l = fmaxf(x1, gx1), r = fminf(x2, gx2);
                float tp = fmaxf(y1, gy1), bo = fminf(y2, gy2);
                float v = 0.f;
                if (l < r && tp < bo) {
                    float inter = (r - l) * (bo - tp);
                    float ag = (gx2 - gx1) * (gy2 - gy1);
                    v = inter / (aa + ag - inter);
                }
                if (!inside) v = 0.f;
                if (v > best) { best = v; bg = g2; }
            }
            idxs = bg;
        }
        int a0 = at * 256;
        int a = a0 + t;
        float mx = 0.f;
        bool inside = false;
        if (a < ANCH) {
            float x1, y1, x2, y2;
            anchor_box(a, x1, y1, x2, y2);
            inside = (x1 >= 0.f) && (y1 >= 0.f) && (x2 < imv[1]) && (y2 < imv[0]);
            float aa = (x2 - x1) * (y2 - y1);
            for (int g2 = 0; g2 < NG; g2++) {
                float gx1 = g4[g2 * 4], gy1 = g4[g2 * 4 + 1], gx2 = g4[g2 * 4 + 2], gy2 = g4[g2 * 4 + 3];
                float l = fmaxf(x1, gx1), r = fminf(x2, gx2);
                float tp = fmaxf(y1, gy1), bo = fminf(y2, gy2);
                float v = 0.f;
                if (l < r && tp < bo) {
                    float inter = (r - l) * (bo - tp);
                    float ag = (gx2 - gx1) * (gy2 - gy1);
                    v = inter / (aa + ag - inter);
                }
                if (!inside) v = 0.f;
                buf[t * NG + g2] = v;
                mx = fmaxf(mx, v);
            }
        }
        __syncthreads();
        int rem = ANCH - a0;
        int cnt2 = (rem < 256 ? rem : 256) * NG;
        float* dst = iou_out + (b * ANCH + a0) * NG;
        for (int i = t; i < cnt2; i += 256) dst[i] = buf[i];
        if (a < ANCH) {
            float lv = (a == idxs) ? 1.f : 0.f;
            if (inside && mx > 0.7f) lv = 0.f;
            lab[b * ANCH + a] = lv;
        }
    }
}

// ---------- fused 1x1 heads + softmax/bias + concat write ----------
// 232 blocks x 4 waves; each wave: 16 rows x 64 cols GEMM -> LDS -> epilogue.
__global__ __launch_bounds__(256) void k_post(const u16* __restrict__ act,
                                              const u16* __restrict__ whd,
                                              const float* __restrict__ bc,
                                              const float* __restrict__ bb,
                                              float* __restrict__ out) {
    __shared__ float Sl[4 * 16 * 65];
    int tid = threadIdx.x;
    int wave = tid >> 6, lane = tid & 63;
    int lm = lane & 15, lq = lane >> 4;
    int m0 = blockIdx.x * 64 + wave * 16;
    int mr = m0 + lm; if (mr > MTOT - 1) mr = MTOT - 1;
    const u16* arow = act + mr * 512;
    f32x4 acc[4] = {};
    for (int kk = 0; kk < 512; kk += 32) {
        bf16x8 a = *(const bf16x8*)&arow[kk + lq * 8];
        #pragma unroll
        for (int j = 0; j < 4; j++) {
            bf16x8 b = *(const bf16x8*)&whd[(j * 16 + lm) * 512 + kk + lq * 8];
            acc[j] = __builtin_amdgcn_mfma_f32_16x16x32_bf16(a, b, acc[j], 0, 0, 0);
        }
    }
    float* S = &Sl[wave * 1040];
    #pragma unroll
    for (int r = 0; r < 4; r++)
        #pragma unroll
        for (int j = 0; j < 4; j++)
            S[(lq * 4 + r) * 65 + j * 16 + lm] = acc[j][r];
    __syncthreads();
    int r16 = lane & 15, cg = lane >> 4;
    int m = m0 + r16;
    if (m < MTOT) {
        int b = m / FHW, hw = m - b * FHW;
        const float* Sr = &S[r16 * 65];
        #pragma unroll
        for (int k = 0; k < 14; k++) {
            int c = cg + 4 * k;
            if (c >= 54) break;
            float v;
            if (c < 18) {
                int c0 = c < 9 ? c : c - 9;
                float s0 = Sr[c0] + bc[c0];
                float s1 = Sr[c0 + 9] + bc[c0 + 9];
                float mx = fmaxf(s0, s1);
                float e0 = __expf(s0 - mx), e1 = __expf(s1 - mx);
                v = (c < 9 ? e0 : e1) / (e0 + e1);
            } else {
                v = Sr[c] + bb[c - 18];
            }
            out[(b * 54 + c) * FHW + hw] = v;
        }
    }
}

extern "C" void kernel_launch(void* const* d_in, const int* in_sizes, int n_in,
                              void* d_out, int out_size, void* d_ws, size_t ws_size,
                              hipStream_t stream) {
    (void)in_sizes; (void)n_in; (void)out_size; (void)ws_size;
    const float* feats = (const float*)d_in[0];
    const float* w3    = (const float*)d_in[1];
    const float* b3    = (const float*)d_in[2];
    const float* wc    = (const float*)d_in[3];
    const float* bc    = (const float*)d_in[4];
    const float* wb    = (const float*)d_in[5];
    const float* bb    = (const float*)d_in[6];
    const float* gt    = (const float*)d_in[7];
    const float* im    = (const float*)d_in[8];
    float* out = (float*)d_out;
    char* ws = (char*)d_ws;

    // workspace layout (bytes)
    u16* apad = (u16*)(ws);                    // 8*39*52*512 bf16 = 16,613,376 B
    u16* wt   = (u16*)(ws + 16613376);         // 512*4608 bf16    =  4,718,592 B
    u16* whd  = (u16*)(ws + 21331968);         // 64*512 bf16      =     65,536 B
    u16* act  = (u16*)(ws + 21397504);         // 14800*512 bf16   = 15,155,200 B

    float* iou_out = out + 799200;
    float* lab     = out + 3463200;

    k_pre<<<dim3(PRE_TOT), dim3(256), 0, stream>>>(apad, w3, wt, wc, wb, whd, feats);
    k_conv<<<dim3(CONVB + IOB), dim3(256), 0, stream>>>(apad, wt, b3, act, gt, im, iou_out, lab);
    k_post<<<dim3(232), dim3(256), 0, stream>>>(act, whd, bc, bb, out);
}

// Round 2
// 203.218 us; speedup vs baseline: 1.1273x; 1.1273x over previous
//
#include <hip/hip_runtime.h>

typedef unsigned short u16;
typedef unsigned int u32;
typedef float f32x4 __attribute__((ext_vector_type(4)));
typedef short bf16x8 __attribute__((ext_vector_type(8)));

#define NB 8
#define FH 37
#define FW 50
#define FHW 1850
#define MTOT 14800
#define CIN 512
#define KTOT 4608
#define HP 39
#define WP 52
#define ANCH 16650
#define NG 20

// k_pre block ranges
#define ZB 356            // pad-ring zero
#define WTB 512           // w3 repack (LDS transpose, 1 block per n)
#define WHB 128           // head-weight repack
#define TRB 3712          // NHWC transpose: 58 hw x 8 ctile x 8 img, u32 stores
#define PRE_TOT (ZB + WTB + WHB + TRB)

// k_conv block ranges
// R2: BM=BN=128 tile -> 116 mb x 4 nb in 15x32 slots (16 dead), XCD swizzle
#define CONVB 480
#define IOB 528           // 66 x 8 iou blocks ride along

// ---------- helpers ----------
__device__ __forceinline__ u16 f2bf(float f) {
    u32 u = __float_as_uint(f);
    u += 0x7fffu + ((u >> 16) & 1u);   // round-to-nearest-even
    return (u16)(u >> 16);
}

__device__ __forceinline__ void gl2lds16(const u16* g, u16* l) {
    __builtin_amdgcn_global_load_lds((const __attribute__((address_space(1))) void*)(g),
                                     (__attribute__((address_space(3))) void*)(l),
                                     16, 0, 0);
}

__device__ __forceinline__ void anchor_box(int a, float& x1, float& y1, float& x2, float& y2) {
    int x = a / 333;
    int rem = a - x * 333;
    int y = rem / 9;
    int r2 = rem - y * 9;
    int si = r2 / 3;
    int bi = r2 - si * 3;
    float s = (float)(8 << si);
    float fx = (float)x, fy = (float)y;
    float ax1, ay1, ax2, ay2;
    if (bi == 0)      { float h = s * 0.5f;  ax1 = fx - h; ay1 = fy - h; ax2 = fx + h; ay2 = fy + h; }
    else if (bi == 1) { float q = s * 0.25f; ax1 = fx - s; ay1 = fy - q; ax2 = fx + s; ay2 = fy + q; }
    else              { float q = s * 0.25f; ax1 = fx - q; ay1 = fy - s; ax2 = fx + q; ay2 = fy + s; }
    x1 = ax1 * 16.f; y1 = ay1 * 16.f; x2 = ax2 * 16.f; y2 = ay2 * 16.f;
}

// ---------- fused prep ----------
__global__ __launch_bounds__(256) void k_pre(u16* __restrict__ apad,
                                             const float* __restrict__ w3, u16* __restrict__ wt,
                                             const float* __restrict__ wc, const float* __restrict__ wb,
                                             u16* __restrict__ whd,
                                             const float* __restrict__ feats) {
    __shared__ __attribute__((aligned(16))) char smraw[18432];
    int blk = blockIdx.x;
    int t = threadIdx.x;

    if (blk < ZB) {
        // zero only the 1-px pad ring (interior overwritten by transpose)
        uint4* apad4 = (uint4*)apad;
        int i = blk * 256 + t;               // < 91136
        int img = i / 11392;
        int r = i - img * 11392;
        int u4;
        if (r < 3328) u4 = r;                                   // row 0
        else if (r < 6656) u4 = 126464 + (r - 3328);            // row 38
        else {
            int rp = r - 6656;
            int h = 1 + (rp >> 7);
            int c2 = rp & 127;
            int col = (c2 & 64) ? 51 : 0;
            u4 = (h * 52 + col) * 64 + (c2 & 63);
        }
        apad4[img * 129792 + u4] = make_uint4(0u, 0u, 0u, 0u);
    } else if (blk < ZB + WTB) {
        // w3[n] (512,3,3) -> wt[n][tap*512+ci], coalesced via LDS transpose
        float* lt = (float*)smraw;           // 4608 floats
        int n = blk - ZB;
        const float* src = w3 + n * KTOT;
        for (int i = t; i < KTOT; i += 256) lt[i] = src[i];
        __syncthreads();
        u16* dst = wt + n * KTOT;
        for (int o = t; o < KTOT; o += 256) {
            int tap = o >> 9, ci = o & 511;
            dst[o] = f2bf(lt[ci * 9 + tap]);
        }
    } else if (blk < ZB + WTB + WHB) {
        int i = (blk - ZB - WTB) * 256 + t;
        int n = i >> 9;
        int ci = i & 511;
        float v = 0.f;
        if (n < 18) v = wc[n * 512 + ci];
        else if (n < 54) v = wb[(n - 18) * 512 + ci];
        whd[i] = f2bf(v);
    } else {
        // feats (B,512,37,50) f32 -> apad (B,39,52,512) bf16 interior.
        // Tile: 32 hw x 64 c; stores pack 2 channels/lane (u32, 128-B segments).
        float* tile = (float*)smraw;         // 64 x 33 floats
        int q = blk - ZB - WTB - WHB;
        int xt = q % 58;
        int r2 = q / 58;
        int ct = r2 & 7;                     // 8 c-tiles of 64
        int img = r2 >> 3;
        int hw0 = xt * 32, c0 = ct * 64;
        int lx = t & 31, ly = t >> 5;        // ly 0..7
        #pragma unroll
        for (int rr = 0; rr < 8; rr++) {
            int cl = ly + rr * 8;            // 0..63
            int hw = hw0 + lx;
            if (hw < FHW) tile[cl * 33 + lx] = feats[(img * 512 + c0 + cl) * FHW + hw];
        }
        __syncthreads();
        #pragma unroll
        for (int rr = 0; rr < 4; rr++) {
            int hwl = ly + rr * 8;           // 0..31
            int hw2 = hw0 + hwl;
            if (hw2 < FHW) {
                int h = hw2 / FW, w = hw2 - h * FW;
                float v0 = tile[(2 * lx) * 33 + hwl];
                float v1 = tile[(2 * lx + 1) * 33 + hwl];
                u32 pk = (u32)f2bf(v0) | ((u32)f2bf(v1) << 16);
                u32* dst = (u32*)&apad[(((img * HP) + h + 1) * WP + (w + 1)) * 512 + c0];
                dst[lx] = pk;
            }
        }
    }
}

// ---------- 3x3 conv as implicit GEMM + IoU tail ----------
// R2: BM=128 BN=128 BK=64, 4 waves each owning a 64x64 sub-tile (square
// wave-tile = max fragment reuse; LDS traffic/FLOP drops 1.5x vs BN=64).
// Single-buffered, 2 barriers per K-step — R1 proved explicit dbuf costs more
// occupancy than it buys latency-hiding (cross-block TLP already covers it).
// XCD decode: all 4 nb of one mb share L%8 (one XCD) for A-tile L2 reuse.
__global__ __launch_bounds__(256) void k_conv(const u16* __restrict__ apad,
                                              const u16* __restrict__ wt,
                                              const float* __restrict__ b3,
                                              u16* __restrict__ act,
                                              const float* __restrict__ gt,
                                              const float* __restrict__ im,
                                              float* __restrict__ iou_out,
                                              float* __restrict__ lab) {
    __shared__ __attribute__((aligned(16))) char sm[32768];
    __shared__ int idxs;
    int L = blockIdx.x;
    int tid = threadIdx.x;

    if (L < CONVB) {
        u16* As = (u16*)sm;                 // 128x64 bf16, 16 KB
        u16* Bs = (u16*)(sm + 16384);       // 128x64 bf16, 16 KB
        int mb = (L & 7) + 8 * (L >> 5);
        int nb = (L >> 3) & 3;
        if (mb >= 116) return;
        int wave = tid >> 6, lane = tid & 63;
        int m0 = mb * 128;
        int n0 = nb * 128;
        int wr = wave >> 1, wn = wave & 1;
        int lm = lane & 15, lq = lane >> 4;
        int l7 = lm & 7;

        f32x4 acc[4][4] = {};

        int rloc = tid >> 3;
        int cg = (tid & 7) ^ (rloc & 7);
        int aBase[4], bBase[4];
        for (int i = 0; i < 4; i++) {
            int m = m0 + i * 32 + rloc; if (m > MTOT - 1) m = MTOT - 1;
            int b = m / FHW; int hw = m - b * FHW;
            int h = hw / FW; int w = hw - h * FW;
            aBase[i] = ((b * HP + h) * WP + w) * 512 + cg * 8;
        }
        for (int j = 0; j < 4; j++)
            bBase[j] = (n0 + j * 32 + rloc) * KTOT + cg * 8;

        u16* aL[4]; u16* bL[4];
        for (int i = 0; i < 4; i++) aL[i] = &As[(i * 32 + wave * 8) * 64];
        for (int j = 0; j < 4; j++) bL[j] = &Bs[(j * 32 + wave * 8) * 64];

        for (int kk = 0; kk < KTOT; kk += 64) {
            int tap = kk >> 9;
            int ci0 = kk & 511;
            int dy = tap / 3, dx = tap - dy * 3;
            int aOfs = (dy * WP + dx) * 512 + ci0;
            gl2lds16(apad + aBase[0] + aOfs, aL[0]);
            gl2lds16(apad + aBase[1] + aOfs, aL[1]);
            gl2lds16(apad + aBase[2] + aOfs, aL[2]);
            gl2lds16(apad + aBase[3] + aOfs, aL[3]);
            gl2lds16(wt + bBase[0] + kk, bL[0]);
            gl2lds16(wt + bBase[1] + kk, bL[1]);
            gl2lds16(wt + bBase[2] + kk, bL[2]);
            gl2lds16(wt + bBase[3] + kk, bL[3]);
            __syncthreads();
            bf16x8 a[2][4], b[2][4];
            #pragma unroll
            for (int ks = 0; ks < 2; ks++) {
                int slotb = ((ks * 4 + lq) ^ l7) * 8;
                #pragma unroll
                for (int i = 0; i < 4; i++)
                    a[ks][i] = *(const bf16x8*)&As[(wr * 64 + i * 16 + lm) * 64 + slotb];
                #pragma unroll
                for (int j = 0; j < 4; j++)
                    b[ks][j] = *(const bf16x8*)&Bs[(wn * 64 + j * 16 + lm) * 64 + slotb];
            }
            #pragma unroll
            for (int ks = 0; ks < 2; ks++)
                #pragma unroll
                for (int i = 0; i < 4; i++)
                    #pragma unroll
                    for (int j = 0; j < 4; j++)
                        acc[i][j] = __builtin_amdgcn_mfma_f32_16x16x32_bf16(a[ks][i], b[ks][j], acc[i][j], 0, 0, 0);
            __syncthreads();
        }

        // epilogue: bias + relu + bf16 act
        for (int j = 0; j < 4; j++) {
            int n = n0 + wn * 64 + j * 16 + lm;
            float bias = b3[n];
            for (int i = 0; i < 4; i++) {
                int mb2 = m0 + wr * 64 + i * 16 + lq * 4;
                for (int r = 0; r < 4; r++) {
                    int m = mb2 + r;
                    if (m < MTOT) {
                        float v = acc[i][j][r] + bias;
                        act[m * 512 + n] = f2bf(v > 0.f ? v : 0.f);
                    }
                }
            }
        }
    } else {
        // IoU matrix + labels (idx fused)
        float* g4 = (float*)sm;              // 80 floats
        float* imv = g4 + 80;                // 2
        float* buf = g4 + 84;                // 256*20
        int q = L - CONVB;
        int at = q % 66;
        int b = q / 66;
        int t = tid;
        if (t < NG * 4) g4[t] = gt[b * NG * 4 + t];
        if (t < 2) imv[t] = im[t];
        __syncthreads();
        if (t == 0) {
            float x1, y1, x2, y2;
            anchor_box(19, x1, y1, x2, y2);
            bool inside = (x1 >= 0.f) && (y1 >= 0.f) && (x2 < imv[1]) && (y2 < imv[0]);
            float aa = (x2 - x1) * (y2 - y1);
            float best = -1.f; int bg = 0;
            for (int g2 = 0; g2 < NG; g2++) {
                float gx1 = g4[g2 * 4], gy1 = g4[g2 * 4 + 1], gx2 = g4[g2 * 4 + 2], gy2 = g4[g2 * 4 + 3];
                float l = fmaxf(x1, gx1), r = fminf(x2, gx2);
                float tp = fmaxf(y1, gy1), bo = fminf(y2, gy2);
                float v = 0.f;
                if (l < r && tp < bo) {
                    float inter = (r - l) * (bo - tp);
                    float ag = (gx2 - gx1) * (gy2 - gy1);
                    v = inter / (aa + ag - inter);
                }
                if (!inside) v = 0.f;
                if (v > best) { best = v; bg = g2; }
            }
            idxs = bg;
        }
        int a0 = at * 256;
        int a = a0 + t;
        float mx = 0.f;
        bool inside = false;
        if (a < ANCH) {
            float x1, y1, x2, y2;
            anchor_box(a, x1, y1, x2, y2);
            inside = (x1 >= 0.f) && (y1 >= 0.f) && (x2 < imv[1]) && (y2 < imv[0]);
            float aa = (x2 - x1) * (y2 - y1);
            for (int g2 = 0; g2 < NG; g2++) {
                float gx1 = g4[g2 * 4], gy1 = g4[g2 * 4 + 1], gx2 = g4[g2 * 4 + 2], gy2 = g4[g2 * 4 + 3];
                float l = fmaxf(x1, gx1), r = fminf(x2, gx2);
                float tp = fmaxf(y1, gy1), bo = fminf(y2, gy2);
                float v = 0.f;
                if (l < r && tp < bo) {
                    float inter = (r - l) * (bo - tp);
                    float ag = (gx2 - gx1) * (gy2 - gy1);
                    v = inter / (aa + ag - inter);
                }
                if (!inside) v = 0.f;
                buf[t * NG + g2] = v;
                mx = fmaxf(mx, v);
            }
        }
        __syncthreads();
        int rem = ANCH - a0;
        int cnt2 = (rem < 256 ? rem : 256) * NG;
        float* dst = iou_out + (b * ANCH + a0) * NG;
        for (int i = t; i < cnt2; i += 256) dst[i] = buf[i];
        if (a < ANCH) {
            float lv = (a == idxs) ? 1.f : 0.f;
            if (inside && mx > 0.7f) lv = 0.f;
            lab[b * ANCH + a] = lv;
        }
    }
}

// ---------- fused 1x1 heads + softmax/bias + concat write ----------
// 232 blocks x 4 waves; each wave: 16 rows x 64 cols GEMM -> LDS -> epilogue.
__global__ __launch_bounds__(256) void k_post(const u16* __restrict__ act,
                                              const u16* __restrict__ whd,
                                              const float* __restrict__ bc,
                                              const float* __restrict__ bb,
                                              float* __restrict__ out) {
    __shared__ float Sl[4 * 16 * 65];
    int tid = threadIdx.x;
    int wave = tid >> 6, lane = tid & 63;
    int lm = lane & 15, lq = lane >> 4;
    int m0 = blockIdx.x * 64 + wave * 16;
    int mr = m0 + lm; if (mr > MTOT - 1) mr = MTOT - 1;
    const u16* arow = act + mr * 512;
    f32x4 acc[4] = {};
    for (int kk = 0; kk < 512; kk += 32) {
        bf16x8 a = *(const bf16x8*)&arow[kk + lq * 8];
        #pragma unroll
        for (int j = 0; j < 4; j++) {
            bf16x8 b = *(const bf16x8*)&whd[(j * 16 + lm) * 512 + kk + lq * 8];
            acc[j] = __builtin_amdgcn_mfma_f32_16x16x32_bf16(a, b, acc[j], 0, 0, 0);
        }
    }
    float* S = &Sl[wave * 1040];
    #pragma unroll
    for (int r = 0; r < 4; r++)
        #pragma unroll
        for (int j = 0; j < 4; j++)
            S[(lq * 4 + r) * 65 + j * 16 + lm] = acc[j][r];
    __syncthreads();
    int r16 = lane & 15, cg = lane >> 4;
    int m = m0 + r16;
    if (m < MTOT) {
        int b = m / FHW, hw = m - b * FHW;
        const float* Sr = &S[r16 * 65];
        #pragma unroll
        for (int k = 0; k < 14; k++) {
            int c = cg + 4 * k;
            if (c >= 54) break;
            float v;
            if (c < 18) {
                int c0 = c < 9 ? c : c - 9;
                float s0 = Sr[c0] + bc[c0];
                float s1 = Sr[c0 + 9] + bc[c0 + 9];
                float mx = fmaxf(s0, s1);
                float e0 = __expf(s0 - mx), e1 = __expf(s1 - mx);
                v = (c < 9 ? e0 : e1) / (e0 + e1);
            } else {
                v = Sr[c] + bb[c - 18];
            }
            out[(b * 54 + c) * FHW + hw] = v;
        }
    }
}

extern "C" void kernel_launch(void* const* d_in, const int* in_sizes, int n_in,
                              void* d_out, int out_size, void* d_ws, size_t ws_size,
                              hipStream_t stream) {
    (void)in_sizes; (void)n_in; (void)out_size; (void)ws_size;
    const float* feats = (const float*)d_in[0];
    const float* w3    = (const float*)d_in[1];
    const float* b3    = (const float*)d_in[2];
    const float* wc    = (const float*)d_in[3];
    const float* bc    = (const float*)d_in[4];
    const float* wb    = (const float*)d_in[5];
    const float* bb    = (const float*)d_in[6];
    const float* gt    = (const float*)d_in[7];
    const float* im    = (const float*)d_in[8];
    float* out = (float*)d_out;
    char* ws = (char*)d_ws;

    // workspace layout (bytes)
    u16* apad = (u16*)(ws);                    // 8*39*52*512 bf16 = 16,613,376 B
    u16* wt   = (u16*)(ws + 16613376);         // 512*4608 bf16    =  4,718,592 B
    u16* whd  = (u16*)(ws + 21331968);         // 64*512 bf16      =     65,536 B
    u16* act  = (u16*)(ws + 21397504);         // 14800*512 bf16   = 15,155,200 B

    float* iou_out = out + 799200;
    float* lab     = out + 3463200;

    k_pre<<<dim3(PRE_TOT), dim3(256), 0, stream>>>(apad, w3, wt, wc, wb, whd, feats);
    k_conv<<<dim3(CONVB + IOB), dim3(256), 0, stream>>>(apad, wt, b3, act, gt, im, iou_out, lab);
    k_post<<<dim3(232), dim3(256), 0, stream>>>(act, whd, bc, bb, out);
}